// Round 3
// baseline (364.878 us; speedup 1.0000x reference)
//
#include <hip/hip_runtime.h>
#include <math.h>

// FactorizationMachine: out = sigmoid( X@fc_w + fc_b + 0.5*( sum_d (X@w)_d^2 - (X^2)@g ) )
// with g[f] = sum_d w[f,d]^2 computed inline.
//
// R2 redesign: R0/R1 at 298-304 us == ~1.9 GB through HBM (X ideal is 819 MB).
// Diagnosis: W logical traffic (blocks x 3.2 MB) misses L2 because streaming X
// evicts it. Fix the reuse geometry:
//  - 32 rows/block = 4 waves x 8 rows; all 4 waves sweep the SAME W addresses
//    (different rows) -> W shared via L1 within the CU.
//  - K-split x8 (F-chunks) restores grid to 1024 blocks; fp32 partials land in
//    d_ws; a tiny phase-2 kernel reduces 8 partials/row + epilogue.
//  - chunk id = blockIdx & 7 -> round-robin dispatch pins each F-chunk to one
//    XCD, so each L2 only needs 400 KB of W resident (vs 3.2 MB before).

constexpr int B_ROWS   = 4096;
constexpr int F_FEAT   = 50000;
constexpr int NF4      = F_FEAT / 4;       // 12500
constexpr int D_FAC    = 16;
constexpr int WAVE_ROWS = 8;
constexpr int WAVES    = 4;
constexpr int GROUP_ROWS = WAVE_ROWS * WAVES;   // 32 rows per block
constexpr int NGROUP   = B_ROWS / GROUP_ROWS;   // 128
constexpr int KSPLIT   = 8;
constexpr int CHUNK_F4 = (NF4 + KSPLIT - 1) / KSPLIT;  // 1563
constexpr int THREADS  = 256;
constexpr int NVAL     = WAVE_ROWS * (D_FAC + 1);      // 136 per wave

typedef float f32x4 __attribute__((ext_vector_type(4)));

__device__ __forceinline__ f32x4 ntload4(const f32x4* p) {
    return __builtin_nontemporal_load(p);
}

__global__ __launch_bounds__(THREADS)
void fm_phase1(const float* __restrict__ X,
               const float* __restrict__ fcw,
               const float* __restrict__ W,
               float* __restrict__ ws)
{
    const int tid  = threadIdx.x;
    const int lane = tid & 63;
    const int wid  = tid >> 6;
    const int c    = blockIdx.x & (KSPLIT - 1);   // F-chunk -> XCD via %8 dispatch
    const int g    = blockIdx.x >> 3;             // row-group
    const int row0 = g * GROUP_ROWS + wid * WAVE_ROWS;
    const int f4_beg = c * CHUNK_F4;
    const int f4_end = min(NF4, f4_beg + CHUNK_F4);

    const f32x4* X4  = reinterpret_cast<const f32x4*>(X);
    const f32x4* W4  = reinterpret_cast<const f32x4*>(W);
    const f32x4* FW4 = reinterpret_cast<const f32x4*>(fcw);

    float s[WAVE_ROWS][D_FAC];
    float lin[WAVE_ROWS];
#pragma unroll
    for (int r = 0; r < WAVE_ROWS; ++r) {
        lin[r] = 0.f;
#pragma unroll
        for (int d = 0; d < D_FAC; ++d) s[r][d] = 0.f;
    }

    // Each WAVE covers the whole chunk (lane-stride-64); the 4 waves of the
    // block read identical W/fcw addresses (L1-shared) for their own 8 rows.
    for (int f4 = f4_beg + lane; f4 < f4_end; f4 += 64) {
        f32x4 xv[WAVE_ROWS];
#pragma unroll
        for (int r = 0; r < WAVE_ROWS; ++r)
            xv[r] = ntload4(&X4[(size_t)(row0 + r) * NF4 + f4]);

        const f32x4 fw = FW4[f4];

#pragma unroll
        for (int j = 0; j < 4; ++j) {          // 4 features of this float4 group
            f32x4 wr[4];                        // w row of feature j (16 floats)
#pragma unroll
            for (int q = 0; q < 4; ++q)
                wr[q] = W4[(size_t)f4 * 16 + 4 * j + q];

            float wd[D_FAC];
#pragma unroll
            for (int t = 0; t < D_FAC; ++t)
                wd[t] = wr[t >> 2][t & 3];

            float gp = 0.f;
#pragma unroll
            for (int t = 0; t < D_FAC; ++t) gp = fmaf(wd[t], wd[t], gp);
            gp *= -0.5f;

            const float fwj = fw[j];
#pragma unroll
            for (int r = 0; r < WAVE_ROWS; ++r) {
                const float x  = xv[r][j];
                const float x2 = x * x;
                lin[r] = fmaf(x, fwj, lin[r]);
                lin[r] = fmaf(x2, gp, lin[r]);
#pragma unroll
                for (int t = 0; t < D_FAC; ++t)
                    s[r][t] = fmaf(x, wd[t], s[r][t]);
            }
        }
    }

    // Per-wave allreduce of 136 values; lane (i&63) keeps value i; coalesced store.
    float keep[3];
    keep[0] = keep[1] = keep[2] = 0.f;
    int idx = 0;
#pragma unroll
    for (int r = 0; r < WAVE_ROWS; ++r) {
#pragma unroll
        for (int t = 0; t <= D_FAC; ++t) {
            float v = (t < D_FAC) ? s[r][t] : lin[r];
#pragma unroll
            for (int m = 32; m >= 1; m >>= 1) v += __shfl_xor(v, m, 64);
            if ((idx & 63) == lane) keep[idx >> 6] = v;
            ++idx;
        }
    }

    // ws layout: [blockIdx][wave][136]
    float* base = ws + ((size_t)blockIdx.x * WAVES + wid) * NVAL;
#pragma unroll
    for (int k = 0; k < 3; ++k) {
        const int i = k * 64 + lane;
        if (i < NVAL) base[i] = keep[k];
    }
}

__global__ __launch_bounds__(256)
void fm_phase2(const float* __restrict__ ws,
               const float* __restrict__ fcb,
               float* __restrict__ out)
{
    const int r = blockIdx.x * 256 + threadIdx.x;
    if (r >= B_ROWS) return;
    const int g   = r / GROUP_ROWS;
    const int wr  = r % GROUP_ROWS;
    const int wid = wr / WAVE_ROWS;
    const int rr  = wr % WAVE_ROWS;

    float acc[D_FAC + 1];
#pragma unroll
    for (int t = 0; t <= D_FAC; ++t) acc[t] = 0.f;

    for (int c = 0; c < KSPLIT; ++c) {
        const float* base = ws + ((size_t)(g * KSPLIT + c) * WAVES + wid) * NVAL
                               + rr * (D_FAC + 1);
#pragma unroll
        for (int t = 0; t <= D_FAC; ++t) acc[t] += base[t];
    }

    float ss = 0.f;
#pragma unroll
    for (int t = 0; t < D_FAC; ++t) ss = fmaf(acc[t], acc[t], ss);

    const float logit = acc[D_FAC] + fcb[0] + 0.5f * ss;
    out[r] = 1.0f / (1.0f + expf(-logit));
}

extern "C" void kernel_launch(void* const* d_in, const int* in_sizes, int n_in,
                              void* d_out, int out_size, void* d_ws, size_t ws_size,
                              hipStream_t stream)
{
    const float* X   = (const float*)d_in[0];
    const float* fcw = (const float*)d_in[1];
    const float* fcb = (const float*)d_in[2];
    const float* W   = (const float*)d_in[3];
    float* out = (float*)d_out;
    float* ws  = (float*)d_ws;   // needs 1024*4*136*4 B = 2.23 MB (ws is ~3.2 GB)

    dim3 grid1(NGROUP * KSPLIT);     // 1024 blocks; chunk = blockIdx & 7 -> XCD
    hipLaunchKernelGGL(fm_phase1, grid1, dim3(THREADS), 0, stream, X, fcw, W, ws);

    dim3 grid2((B_ROWS + 255) / 256);
    hipLaunchKernelGGL(fm_phase2, grid2, dim3(256), 0, stream, ws, fcb, out);
}